// Round 3
// baseline (193.388 us; speedup 1.0000x reference)
//
#include <hip/hip_runtime.h>
#include <hip/hip_bf16.h>
#include <math.h>

#define TPB 256

typedef __attribute__((ext_vector_type(8))) short s16x8;
typedef __attribute__((ext_vector_type(4))) float f32x4;

#define MFMA16(a, b, c) __builtin_amdgcn_mfma_f32_16x16x32_bf16((a), (b), (c), 0, 0, 0)

// ---------------- workspace layout (float offsets) ----------------
// p is never materialized anymore (lives in kA's LDS). ABF/WBF gone.
constexpr unsigned OFF_K    = 0u;                     // k    [4096][64]
constexpr unsigned OFF_R    = OFF_K    + 4096u*64u;   // r    [512][64]
constexpr unsigned OFF_SR   = OFF_R    + 512u*64u;    // SR   [512][64]
constexpr unsigned OFF_PMAX = OFF_SR   + 512u*64u;    // PMAX [64] (atomicMax, zeroed by kA tail)
constexpr unsigned OFF_SP   = OFF_PMAX + 64u;         // SP   [4096][64]
constexpr unsigned OFF_PAT  = OFF_SP   + 4096u*64u;   // paT  [64][4096]
constexpr unsigned OFF_RAT  = OFF_PAT  + 64u*4096u;   // raT  [64][512]

// scalar RNE fp32 -> bf16
__device__ __forceinline__ short f2bf(float x) {
  union { float f; unsigned u; } v; v.f = x;
  unsigned r = v.u + 0x7FFFu + ((v.u >> 16) & 1u);
  return (short)(r >> 16);
}
// packed RNE: 2 floats -> 2 bf16 in one dword
__device__ __forceinline__ unsigned pkbf(float a, float b) {
  __hip_bfloat162 h = __float22bfloat162_rn(make_float2(a, b));
  union { __hip_bfloat162 h2; unsigned u; } v; v.h2 = h;
  return v.u;
}
union U8 { s16x8 s; unsigned u[4]; };

// ============================================================================
// KA: fused k0+k1+k2. 145 blocks.
//  bid<128 (protein): compute own p-strip GEMM
//     p[32][256] = relu(prot[row0:+32][1024] @ Wc^T + bc)  (BK=64, inline cvt,
//     register prefetch — same K-accumulation order as the verified k1, so p
//     is bitwise identical) -> bf16 directly into LDS Psm. No global p.
//     Wc (1MB) is L2-resident across the 128 re-reads.
//  bid in [128,144) (reaction): stage reactions rows -> Psm.
//  Then (all): head1 k=relu(Psm@W^T+b) -> global + Ksm; head2 -> paT/raT.
//  bid==144: zero PMAX, exit.
// LDS arena 64512B, phase-overlaid:
//   Psm  [32][264] @ 0       (persists phase0 -> heads)
//   phase0: Asm0 [32][72] @ 16896, Bsm0 [256][72] @ 21504
//   heads : BsmW [64][264] @ 16896, Wsm [64][72] @ 50688, Ksm [32][72] @ 59904
// ============================================================================
__global__ __launch_bounds__(TPB) void kA_fused(
    const float* __restrict__ prot, const float* __restrict__ Wc,
    const float* __restrict__ bc,
    const float* __restrict__ reactions,
    const float* __restrict__ W1,  const float* __restrict__ b1,
    const float* __restrict__ W2,  const float* __restrict__ b2,
    const float* __restrict__ Wpa, const float* __restrict__ bpa,
    const float* __restrict__ Wra, const float* __restrict__ bra,
    float* __restrict__ ws)
{
  int bid = blockIdx.x, tid = threadIdx.x;
  if (bid >= 144) {
    if (tid < 16)
      *(float4*)&ws[OFF_PMAX + tid * 4] = make_float4(0.f, 0.f, 0.f, 0.f);
    return;
  }
  __shared__ __align__(16) unsigned char SM[64512];
  short* Psm  = (short*)(SM);            // [32][264]
  short* Asm0 = (short*)(SM + 16896);    // [32][72]   (phase0)
  short* Bsm0 = (short*)(SM + 21504);    // [256][72]  (phase0)
  short* BsmW = (short*)(SM + 16896);    // [64][264]  (heads)
  short* Wsm  = (short*)(SM + 50688);    // [64][72]   (heads)
  short* Ksm  = (short*)(SM + 59904);    // [32][72]   (heads)

  int wave = tid >> 6, lane = tid & 63;
  int lm = lane & 15, quad = lane >> 4;
  bool isProt = bid < 128;
  int row0 = (isProt ? bid : (bid - 128)) * 32;

  if (isProt) {
    // ---------------- phase 0: p-strip GEMM into Psm ----------------
    int arow = tid >> 3, aseg = (tid & 7) * 8;     // A: 32 rows x 8x8 floats
    const float* Ag = prot + (size_t)(row0 + arow) * 1024 + aseg;
    const float* Bg = Wc + (size_t)tid * 1024;     // one Wc row per thread
    int wm = (wave & 1) * 16, wn = (wave >> 1) * 128;  // wave tile 16x128

    float4 a4[2], b4[16];
#pragma unroll
    for (int i = 0; i < 2; ++i) a4[i] = *(const float4*)(Ag + i * 4);
#pragma unroll
    for (int i = 0; i < 16; ++i) b4[i] = *(const float4*)(Bg + i * 4);

    f32x4 acc0[8] = {};
    for (int kc = 0; kc < 16; ++kc) {
      __syncthreads();                  // previous chunk's frag reads done
      {
        U8 s;
        s.u[0] = pkbf(a4[0].x, a4[0].y); s.u[1] = pkbf(a4[0].z, a4[0].w);
        s.u[2] = pkbf(a4[1].x, a4[1].y); s.u[3] = pkbf(a4[1].z, a4[1].w);
        *(s16x8*)&Asm0[arow * 72 + aseg] = s.s;
      }
#pragma unroll
      for (int h = 0; h < 8; ++h) {
        U8 s;
        s.u[0] = pkbf(b4[2*h].x,   b4[2*h].y);
        s.u[1] = pkbf(b4[2*h].z,   b4[2*h].w);
        s.u[2] = pkbf(b4[2*h+1].x, b4[2*h+1].y);
        s.u[3] = pkbf(b4[2*h+1].z, b4[2*h+1].w);
        *(s16x8*)&Bsm0[tid * 72 + h * 8] = s.s;
      }
      if (kc < 15) {                    // prefetch next chunk over this MFMA
#pragma unroll
        for (int i = 0; i < 2; ++i) a4[i] = *(const float4*)(Ag + (kc + 1) * 64 + i * 4);
#pragma unroll
        for (int i = 0; i < 16; ++i) b4[i] = *(const float4*)(Bg + (kc + 1) * 64 + i * 4);
      }
      __syncthreads();
#pragma unroll
      for (int ks = 0; ks < 2; ++ks) {
        s16x8 a = *(const s16x8*)&Asm0[(wm + lm) * 72 + ks * 32 + quad * 8];
#pragma unroll
        for (int nf = 0; nf < 8; ++nf) {
          s16x8 b = *(const s16x8*)&Bsm0[(wn + nf * 16 + lm) * 72 + ks * 32 + quad * 8];
          acc0[nf] = MFMA16(a, b, acc0[nf]);
        }
      }
    }
    // epilogue: C/D layout col=lane&15, row=quad*4+reg -> Psm bf16
#pragma unroll
    for (int nf = 0; nf < 8; ++nf) {
      int col = wn + nf * 16 + lm;
      float bcv = bc[col];
#pragma unroll
      for (int r = 0; r < 4; ++r) {
        int row = wm + quad * 4 + r;
        Psm[row * 264 + col] = f2bf(fmaxf(acc0[nf][r] + bcv, 0.f));
      }
    }
  } else {
    // reaction block: stage reactions [32][256] fp32 -> bf16 -> Psm
    int row = tid >> 3, seg = (tid & 7) * 32;
    const float* sp = reactions + (size_t)(row0 + row) * 256 + seg;
    float4 f[8];
#pragma unroll
    for (int i = 0; i < 8; ++i) f[i] = *(const float4*)(sp + i * 4);
#pragma unroll
    for (int i = 0; i < 4; ++i) {
      U8 s;
      s.u[0] = pkbf(f[2*i].x,   f[2*i].y);
      s.u[1] = pkbf(f[2*i].z,   f[2*i].w);
      s.u[2] = pkbf(f[2*i+1].x, f[2*i+1].y);
      s.u[3] = pkbf(f[2*i+1].z, f[2*i+1].w);
      *(s16x8*)&Psm[row * 264 + seg + i * 8] = s.s;
    }
  }
  __syncthreads();                      // Psm done; phase0 staging region free

  // ---------------- stage head weights ----------------
  const float* Wst1 = isProt ? W1 : W2;
  const float* bv   = isProt ? b1 : b2;
  const float* Wst2 = isProt ? Wpa : Wra;
  const float* b2nd = isProt ? bpa : bra;
  float* out1  = ws + (isProt ? OFF_K : OFF_R);
  float* out2T = ws + (isProt ? OFF_PAT : OFF_RAT);
  unsigned tstride = isProt ? 4096u : 512u;

  {                                     // W1/W2 [64][256] -> BsmW
    int row = tid >> 2, seg = (tid & 3) * 64;
    const float* sp = Wst1 + (size_t)row * 256 + seg;
#pragma unroll
    for (int i = 0; i < 8; ++i) {
      float4 fa = *(const float4*)(sp + i * 8);
      float4 fb = *(const float4*)(sp + i * 8 + 4);
      U8 s;
      s.u[0] = pkbf(fa.x, fa.y); s.u[1] = pkbf(fa.z, fa.w);
      s.u[2] = pkbf(fb.x, fb.y); s.u[3] = pkbf(fb.z, fb.w);
      *(s16x8*)&BsmW[row * 264 + seg + i * 8] = s.s;
    }
  }
  {                                     // Wpa/Wra [64][64] -> Wsm
    int row = tid >> 2, seg = (tid & 3) * 16;
    const float* sp = Wst2 + (size_t)row * 64 + seg;
#pragma unroll
    for (int i = 0; i < 2; ++i) {
      float4 fa = *(const float4*)(sp + i * 8);
      float4 fb = *(const float4*)(sp + i * 8 + 4);
      U8 s;
      s.u[0] = pkbf(fa.x, fa.y); s.u[1] = pkbf(fa.z, fa.w);
      s.u[2] = pkbf(fb.x, fb.y); s.u[3] = pkbf(fb.z, fb.w);
      *(s16x8*)&Wsm[row * 72 + seg + i * 8] = s.s;
    }
  }
  __syncthreads();

  // ---------------- head 1: k = relu(Psm @ W^T + b) ----------------
  int wm1 = (wave >> 1) * 16, wn1 = (wave & 1) * 32;   // wave tile 16x32
  f32x4 acc[2] = {};
#pragma unroll
  for (int kc = 0; kc < 8; ++kc) {
    s16x8 a = *(const s16x8*)&Psm[(wm1 + lm) * 264 + kc * 32 + quad * 8];
#pragma unroll
    for (int ni = 0; ni < 2; ++ni) {
      s16x8 b = *(const s16x8*)&BsmW[(wn1 + ni * 16 + lm) * 264 + kc * 32 + quad * 8];
      acc[ni] = MFMA16(a, b, acc[ni]);
    }
  }
#pragma unroll
  for (int ni = 0; ni < 2; ++ni) {
    int col = wn1 + ni * 16 + lm;
    float bb = bv[col];
#pragma unroll
    for (int r = 0; r < 4; ++r) {
      int row = wm1 + quad * 4 + r;
      float kv = fmaxf(acc[ni][r] + bb, 0.f);
      out1[(size_t)(row0 + row) * 64 + col] = kv;
      Ksm[row * 72 + col] = f2bf(kv);
    }
  }
  __syncthreads();

  // ---------------- head 2: pa/ra = Ksm @ W2nd^T + b -> transposed ----------
  f32x4 acc2[2] = {};
#pragma unroll
  for (int kc = 0; kc < 2; ++kc) {
    s16x8 a = *(const s16x8*)&Ksm[(wm1 + lm) * 72 + kc * 32 + quad * 8];
#pragma unroll
    for (int ni = 0; ni < 2; ++ni) {
      s16x8 b = *(const s16x8*)&Wsm[(wn1 + ni * 16 + lm) * 72 + kc * 32 + quad * 8];
      acc2[ni] = MFMA16(a, b, acc2[ni]);
    }
  }
#pragma unroll
  for (int ni = 0; ni < 2; ++ni) {
    int col = wn1 + ni * 16 + lm;
    float bb = b2nd[col];
#pragma unroll
    for (int r = 0; r < 4; ++r) {
      int row = wm1 + quad * 4 + r;
      float v = acc2[ni][r] + bb;
      out2T[(size_t)col * tstride + (row0 + row)] = v;   // transposed copy
    }
  }
}

// ============================================================================
// K3h: histogram interaction sums. 128 blocks; columns staged from the kA-
// written transposed copies as contiguous coalesced float4 reads.
//   Sr[q,c] = u*cnt(x > -u) + sum(x > -u) via 1024-bin hist + suffix scan.
//   bid<64 : pass A: hist of pa-column c -> 512 SR queries
//   bid>=64: pass B: hist of ra-column c -> 4096 SP queries
// ============================================================================
__global__ __launch_bounds__(TPB) void k3h_hist(float* __restrict__ ws)
{
  __shared__ float xcol[4096];          // pa column
  __shared__ float rcol[512];           // ra column
  __shared__ float hc[1025];            // bin counts -> suffix counts
  __shared__ float hs[1025];            // bin sums   -> suffix sums
  __shared__ float rmn[4], rmx[4];
  int bid = blockIdx.x, tid = threadIdx.x;
  int wave = tid >> 6, lane = tid & 63;
  bool passA = bid < 64;
  int c = passA ? bid : (bid - 64);
  const float* paT = ws + OFF_PAT + (size_t)c * 4096;
  const float* raT = ws + OFF_RAT + (size_t)c * 512;

  for (int i = tid * 4; i < 4096; i += TPB * 4)
    *(float4*)&xcol[i] = *(const float4*)(paT + i);
  if (tid * 4 < 512)
    *(float4*)&rcol[tid * 4] = *(const float4*)(raT + tid * 4);
  for (int i = tid; i < 1025; i += TPB) { hc[i] = 0.f; hs[i] = 0.f; }
  __syncthreads();

  const float* hsrc = passA ? xcol : rcol;  // histogram source
  int hn = passA ? 4096 : 512;
  float mn = 1e30f, mx = -1e30f;
  for (int i = tid; i < hn; i += TPB) {
    float x = hsrc[i];
    mn = fminf(mn, x); mx = fmaxf(mx, x);
  }
#pragma unroll
  for (int off = 32; off > 0; off >>= 1) {
    mn = fminf(mn, __shfl_down(mn, off));
    mx = fmaxf(mx, __shfl_down(mx, off));
  }
  if (lane == 0) { rmn[wave] = mn; rmx[wave] = mx; }
  __syncthreads();
  mn = fminf(fminf(rmn[0], rmn[1]), fminf(rmn[2], rmn[3]));
  mx = fmaxf(fmaxf(rmx[0], rmx[1]), fmaxf(rmx[2], rmx[3]));
  float w = (mx - mn) * (1.f / 1024.f);
  float invw = (w > 1e-30f) ? 1.f / w : 0.f;
  for (int i = tid; i < hn; i += TPB) {
    float x = hsrc[i];
    int b = (int)((x - mn) * invw);
    b = b < 0 ? 0 : (b > 1023 ? 1023 : b);
    atomicAdd(&hc[b], 1.f);
    atomicAdd(&hs[b], x);
  }
  __syncthreads();
  if (wave == 0) {                      // suffix scan, 16 bins/lane + shfl
    float vc[16], vs[16], sc = 0.f, ss = 0.f;
#pragma unroll
    for (int i = 0; i < 16; ++i) {
      vc[i] = hc[lane * 16 + i]; sc += vc[i];
      vs[i] = hs[lane * 16 + i]; ss += vs[i];
    }
    float tc = sc, ts = ss;
#pragma unroll
    for (int off = 1; off < 64; off <<= 1) {
      float oc = __shfl_down(tc, off);
      float os = __shfl_down(ts, off);
      if (lane + off < 64) { tc += oc; ts += os; }
    }
    float runc = tc - sc, runs = ts - ss;
#pragma unroll
    for (int i = 15; i >= 0; --i) {
      runc += vc[i]; hc[lane * 16 + i] = runc;
      runs += vs[i]; hs[lane * 16 + i] = runs;
    }
  }
  __syncthreads();                      // hc/hs = inclusive suffix; [1024]=0

  if (passA) {                          // 512 SR queries (u from rcol)
    for (int q = tid; q < 512; q += TPB) {
      float u = rcol[q];
      float thr = -u;
      int b;
      if (thr < mn) b = 0;
      else { b = (int)((thr - mn) * invw) + 1; b = b > 1024 ? 1024 : b; }
      ws[OFF_SR + (unsigned)q * 64u + c] = u * hc[b] + hs[b];
    }
  } else {                              // 4096 SP queries (v from xcol)
    for (int l = tid; l < 4096; l += TPB) {
      float v = xcol[l];
      float thr = -v;
      int b;
      if (thr < mn) b = 0;
      else { b = (int)((thr - mn) * invw) + 1; b = b > 1024 ? 1024 : b; }
      ws[OFF_SP + (unsigned)l * 64u + c] = v * hc[b] + hs[b];
    }
  }
}

// ============================================================================
// K3b: gate pass. 256 blocks x 16 l-rows:
// p_gate = sigmoid(SP/512 @ Wa^T + ba); val = k*(1+gate); atomicMax PMAX.
// ============================================================================
__global__ __launch_bounds__(TPB) void k3b_gate(
    const float* __restrict__ Wa, const float* __restrict__ ba,
    float* __restrict__ ws)
{
  __shared__ float sp[16 * 64];
  __shared__ float wat[64 * 65];
  int bid = blockIdx.x, tid = threadIdx.x;
  int c = tid & 63, g = tid >> 6;
  int l0 = bid * 16;
  {                                     // stage SP tile (x 1/512)
    int idx = tid * 4;
    float4 v = *(const float4*)&ws[OFF_SP + (unsigned)l0 * 64u + idx];
    v.x *= (1.f / 512.f); v.y *= (1.f / 512.f);
    v.z *= (1.f / 512.f); v.w *= (1.f / 512.f);
    *(float4*)&sp[idx] = v;
  }
  for (int it = 0; it < 16; ++it) {     // WaT[c'][j] = Wa[j][c']
    int idx = it * TPB + tid;
    wat[(idx & 63) * 65 + (idx >> 6)] = Wa[idx];
  }
  __syncthreads();
  float vmax = 0.f;                     // vals >= 0 (k>=0, gate>0)
  float bac = ba[c];
#pragma unroll
  for (int i = 0; i < 4; ++i) {
    int ll = g * 4 + i;
    float dot = 0.f;
#pragma unroll 8
    for (int jj = 0; jj < 64; ++jj)
      dot += sp[ll * 64 + jj] * wat[jj * 65 + c];
    float pg = 1.f / (1.f + __expf(-(dot + bac)));
    float val = ws[OFF_K + (unsigned)(l0 + ll) * 64u + c] * (1.f + pg);
    vmax = fmaxf(vmax, val);
  }
  atomicMax((int*)&ws[OFF_PMAX + c], __float_as_int(vmax));
}

// ============================================================================
// K4: merged final stage, 32 blocks x 16 q. All matmul-shaped pieces as MFMA.
// ============================================================================
__global__ __launch_bounds__(TPB) void k4_final(
    const float* __restrict__ Wa,  const float* __restrict__ ba,
    const float* __restrict__ Wf1, const float* __restrict__ bf1,
    const float* __restrict__ Wf2, const float* __restrict__ bf2,
    const float* __restrict__ Wf3, const float* __restrict__ bf3,
    float* __restrict__ ws, float* __restrict__ out)
{
  __shared__ __align__(16) short mrb[16 * 72];     // mr bf16 (A for gate)
  __shared__ __align__(16) short wab[64 * 72];     // Wa bf16 (B for gate)
  __shared__ __align__(16) short ctxb[16 * 136];   // ctx bf16 (A for h1)
  __shared__ __align__(16) short h1b[16 * 264];    // h1 bf16 (A for h2)
  __shared__ __align__(16) short wgt[256 * 136];   // Wf1 [256][136] then Wf2 [128][264]
  __shared__ float red[64];
  int bid = blockIdx.x, tid = threadIdx.x;
  int q0 = bid * 16;
  int wave = tid >> 6, lane = tid & 63;
  int lm = lane & 15, quad = lane >> 4;

  {                                     // stage mr = SR/4096 -> bf16 [16][72]
    int q = tid >> 4, c4 = (tid & 15) * 4;
    float4 v = *(const float4*)&ws[OFF_SR + (unsigned)(q0 + q) * 64u + c4];
    uint2 st = make_uint2(pkbf(v.x * (1.f/4096.f), v.y * (1.f/4096.f)),
                          pkbf(v.z * (1.f/4096.f), v.w * (1.f/4096.f)));
    *(uint2*)&mrb[q * 72 + c4] = st;
  }
#pragma unroll
  for (int it = 0; it < 4; ++it) {      // stage Wa [64][64] -> bf16 [64][72]
    int i4 = it * TPB + tid;
    int row = i4 >> 4, c4 = (i4 & 15) * 4;
    float4 v = *(const float4*)&Wa[row * 64 + c4];
    uint2 st = make_uint2(pkbf(v.x, v.y), pkbf(v.z, v.w));
    *(uint2*)&wab[row * 72 + c4] = st;
  }
  __syncthreads();

  // gate MFMA: wave w -> c-tile [w*16, w*16+16)
  f32x4 gacc = {};
#pragma unroll
  for (int kc = 0; kc < 2; ++kc) {
    s16x8 a = *(const s16x8*)&mrb[lm * 72 + kc * 32 + quad * 8];
    s16x8 b = *(const s16x8*)&wab[(wave * 16 + lm) * 72 + kc * 32 + quad * 8];
    gacc = MFMA16(a, b, gacc);
  }
  {                                     // epilogue: rx + prot halves -> ctxb
    int c = wave * 16 + lm;
    float bac = ba[c];
    short pb = f2bf(ws[OFF_PMAX + c]);  // prot[c] (atomicMax result)
#pragma unroll
    for (int r = 0; r < 4; ++r) {
      int q = quad * 4 + r;
      float gg = 1.f / (1.f + __expf(-(gacc[r] + bac)));
      float rv = ws[OFF_R + (unsigned)(q0 + q) * 64u + c];
      ctxb[q * 136 + c]      = f2bf(rv * (1.f + gg));
      ctxb[q * 136 + 64 + c] = pb;
    }
  }
#pragma unroll 4
  for (int it = 0; it < 32; ++it) {     // stage Wf1 [256][128] -> wgt [256][136]
    int i4 = it * TPB + tid;
    int row = i4 >> 5, c4 = (i4 & 31) * 4;
    float4 v = *(const float4*)&Wf1[row * 128 + c4];
    uint2 st = make_uint2(pkbf(v.x, v.y), pkbf(v.z, v.w));
    *(uint2*)&wgt[row * 136 + c4] = st;
  }
  __syncthreads();

  // h1 MFMA: wave w covers n in [w*64, w*64+64): 4 n-tiles x 4 k-chunks
  f32x4 h[4] = {};
#pragma unroll
  for (int kc = 0; kc < 4; ++kc) {
    s16x8 a = *(const s16x8*)&ctxb[lm * 136 + kc * 32 + quad * 8];
#pragma unroll
    for (int nt = 0; nt < 4; ++nt) {
      s16x8 b = *(const s16x8*)&wgt[(wave * 64 + nt * 16 + lm) * 136 + kc * 32 + quad * 8];
      h[nt] = MFMA16(a, b, h[nt]);
    }
  }
#pragma unroll
  for (int nt = 0; nt < 4; ++nt) {
    int n = wave * 64 + nt * 16 + lm;
    float bb = bf1[n];
#pragma unroll
    for (int r = 0; r < 4; ++r) {
      int q = quad * 4 + r;
      float v = h[nt][r] + bb;
      v = v > 0.f ? v : 0.01f * v;
      h1b[q * 264 + n] = f2bf(v);
    }
  }
  __syncthreads();                      // h1b complete; wgt reads done

#pragma unroll 4
  for (int it = 0; it < 32; ++it) {     // stage Wf2 [128][256] -> wgt [128][264]
    int i4 = it * TPB + tid;
    int row = i4 >> 6, c4 = (i4 & 63) * 4;
    float4 v = *(const float4*)&Wf2[row * 256 + c4];
    uint2 st = make_uint2(pkbf(v.x, v.y), pkbf(v.z, v.w));
    *(uint2*)&wgt[row * 264 + c4] = st;
  }
  __syncthreads();

  // h2 MFMA: wave w covers m in [w*32, w*32+32): 2 n-tiles x 8 k-chunks
  f32x4 o[2] = {};
#pragma unroll
  for (int kc = 0; kc < 8; ++kc) {
    s16x8 a = *(const s16x8*)&h1b[lm * 264 + kc * 32 + quad * 8];
#pragma unroll
    for (int nt = 0; nt < 2; ++nt) {
      s16x8 b = *(const s16x8*)&wgt[(wave * 32 + nt * 16 + lm) * 264 + kc * 32 + quad * 8];
      o[nt] = MFMA16(a, b, o[nt]);
    }
  }
  float pv[4] = {0.f, 0.f, 0.f, 0.f};
#pragma unroll
  for (int nt = 0; nt < 2; ++nt) {
    int m = wave * 32 + nt * 16 + lm;
    float bb = bf2[m], w3 = Wf3[m];
#pragma unroll
    for (int r = 0; r < 4; ++r) {
      float v = o[nt][r] + bb;
      v = v > 0.f ? v : 0.01f * v;
      pv[r] += v * w3;
    }
  }
#pragma unroll
  for (int msk = 1; msk < 16; msk <<= 1)
#pragma unroll
    for (int r = 0; r < 4; ++r) pv[r] += __shfl_xor(pv[r], msk);
  if (lm == 0) {
#pragma unroll
    for (int r = 0; r < 4; ++r) red[(quad * 4 + r) * 4 + wave] = pv[r];
  }
  __syncthreads();
  if (tid < 16)
    out[q0 + tid] = red[tid * 4] + red[tid * 4 + 1] + red[tid * 4 + 2] +
                    red[tid * 4 + 3] + bf3[0];
}

// ============================================================================
extern "C" void kernel_launch(void* const* d_in, const int* in_sizes, int n_in,
                              void* d_out, int out_size, void* d_ws, size_t ws_size,
                              hipStream_t stream)
{
  const float* reactions = (const float*)d_in[0];
  const float* protein   = (const float*)d_in[1];
  const float* Wc  = (const float*)d_in[2];
  const float* bc  = (const float*)d_in[3];
  const float* W1  = (const float*)d_in[4];
  const float* b1  = (const float*)d_in[5];
  const float* W2  = (const float*)d_in[6];
  const float* b2  = (const float*)d_in[7];
  const float* Wa  = (const float*)d_in[8];
  const float* ba  = (const float*)d_in[9];
  const float* Wpa = (const float*)d_in[10];
  const float* bpa = (const float*)d_in[11];
  const float* Wra = (const float*)d_in[12];
  const float* bra = (const float*)d_in[13];
  const float* Wf1 = (const float*)d_in[14];
  const float* bf1 = (const float*)d_in[15];
  const float* Wf2 = (const float*)d_in[16];
  const float* bf2 = (const float*)d_in[17];
  const float* Wf3 = (const float*)d_in[18];
  const float* bf3 = (const float*)d_in[19];
  float* ws  = (float*)d_ws;
  float* out = (float*)d_out;

  hipLaunchKernelGGL(kA_fused, dim3(145), dim3(TPB), 0, stream,
                     protein, Wc, bc, reactions,
                     W1, b1, W2, b2, Wpa, bpa, Wra, bra, ws);
  hipLaunchKernelGGL(k3h_hist, dim3(128), dim3(TPB), 0, stream, ws);
  hipLaunchKernelGGL(k3b_gate, dim3(256), dim3(TPB), 0, stream, Wa, ba, ws);
  hipLaunchKernelGGL(k4_final, dim3(32), dim3(TPB), 0, stream,
                     Wa, ba, Wf1, bf1, Wf2, bf2, Wf3, bf3, ws, out);
}

// Round 5
// 168.132 us; speedup vs baseline: 1.1502x; 1.1502x over previous
//
#include <hip/hip_runtime.h>
#include <hip/hip_bf16.h>
#include <math.h>

#define TPB 256

typedef __attribute__((ext_vector_type(8))) short s16x8;
typedef __attribute__((ext_vector_type(4))) float f32x4;

#define MFMA16(a, b, c) __builtin_amdgcn_mfma_f32_16x16x32_bf16((a), (b), (c), 0, 0, 0)

// ---------------- workspace layout (float offsets) ----------------
constexpr unsigned OFF_K    = 0u;                     // k    [4096][64] fp32
constexpr unsigned OFF_R    = OFF_K    + 4096u*64u;   // r    [512][64] fp32
constexpr unsigned OFF_SRT  = OFF_R    + 512u*64u;    // SR^T [64][512] fp32 (c-major)
constexpr unsigned OFF_PMAX = OFF_SRT  + 64u*512u;    // PMAX [64] (atomicMax, zeroed by k0 tail)
constexpr unsigned OFF_SPT  = OFF_PMAX + 64u;         // SP^T [64][4096] fp32 (c-major)
constexpr unsigned OFF_PAT  = OFF_SPT  + 64u*4096u;   // paT  [64][4096]
constexpr unsigned OFF_RAT  = OFF_PAT  + 64u*4096u;   // raT  [64][512]
constexpr unsigned OFF_PBF  = OFF_RAT  + 64u*512u;    // p bf16 [4096][256] shorts = 524288 float slots
constexpr unsigned OFF_ABF  = OFF_PBF  + 524288u;     // protein bf16 [4096][1024] shorts (FIXED: was +262144 — P stores overran into ABF, racing k1's A reads)
constexpr unsigned OFF_WBF  = OFF_ABF  + 2097152u;    // Wc bf16 [256][1024] shorts

// scalar RNE fp32 -> bf16
__device__ __forceinline__ short f2bf(float x) {
  union { float f; unsigned u; } v; v.f = x;
  unsigned r = v.u + 0x7FFFu + ((v.u >> 16) & 1u);
  return (short)(r >> 16);
}
// packed RNE: 2 floats -> 2 bf16 in one dword
__device__ __forceinline__ unsigned pkbf(float a, float b) {
  __hip_bfloat162 h = __float22bfloat162_rn(make_float2(a, b));
  union { __hip_bfloat162 h2; unsigned u; } v; v.h2 = h;
  return v.u;
}
union U8 { s16x8 s; unsigned u[4]; };

// ============================================================================
// K0: one-shot fp32 -> bf16 conversion of protein [4096][1024] and Wc
// [256][1024] into ws (RNE identical to downstream pkbf use -> numerics
// unchanged). Memory-bound: ~17.8MB read + ~8.9MB write.
// Tail block 2176: zero PMAX.
// ============================================================================
__global__ __launch_bounds__(TPB) void k0_cvt(
    const float* __restrict__ prot, const float* __restrict__ Wc,
    float* __restrict__ ws)
{
  int bid = blockIdx.x, tid = threadIdx.x;
  if (bid >= 2176) {
    if (tid < 16)
      *(float4*)&ws[OFF_PMAX + tid * 4] = make_float4(0.f, 0.f, 0.f, 0.f);
    return;
  }
  const float* src; short* dst; size_t idx;
  if (bid < 2048) {
    src = prot; dst = (short*)(ws + OFF_ABF);
    idx = (size_t)bid * 2048 + (size_t)tid * 8;
  } else {
    src = Wc;   dst = (short*)(ws + OFF_WBF);
    idx = (size_t)(bid - 2048) * 2048 + (size_t)tid * 8;
  }
  float4 f0 = *(const float4*)(src + idx);
  float4 f1 = *(const float4*)(src + idx + 4);
  U8 s;
  s.u[0] = pkbf(f0.x, f0.y); s.u[1] = pkbf(f0.z, f0.w);
  s.u[2] = pkbf(f1.x, f1.y); s.u[3] = pkbf(f1.z, f1.w);
  *(s16x8*)(dst + idx) = s.s;
}

// ============================================================================
// K1: p = relu(Abf @ Wbf^T + bc) — pure bf16 MFMA GEMM, zero conversion VALU.
// 256 blocks (1/CU), tile 64x64, BK=128 (8 chunks), register prefetch.
// p written as bf16 (OFF_PBF) — its only consumer (k2 A-staging) converts to
// bf16 anyway, so downstream is bit-identical with half the traffic.
// ============================================================================
__global__ __launch_bounds__(TPB) void k1_gemm(
    const float* __restrict__ bc, float* __restrict__ ws)
{
  __shared__ __align__(16) short Asm[64 * 136];
  __shared__ __align__(16) short Bsm[64 * 136];
  int bid = blockIdx.x, tid = threadIdx.x;
  int m0 = (bid >> 2) * 64, n0 = (bid & 3) * 64;
  int wave = tid >> 6, lane = tid & 63;
  int lm = lane & 15, quad = lane >> 4;
  int wm = (wave & 1) * 32, wn = (wave >> 1) * 32;   // wave tile 32x32

  const short* Abf = (const short*)(ws + OFF_ABF);
  const short* Wbf = (const short*)(ws + OFF_WBF);
  int srow = tid >> 2, sc = (tid & 3) * 32;          // 64 rows x 128 elems
  const short* Ag = Abf + (size_t)(m0 + srow) * 1024 + sc;
  const short* Bg = Wbf + (size_t)(n0 + srow) * 1024 + sc;

  s16x8 ar[4], br[4];
#pragma unroll
  for (int i = 0; i < 4; ++i) {
    ar[i] = *(const s16x8*)(Ag + i * 8);
    br[i] = *(const s16x8*)(Bg + i * 8);
  }

  f32x4 acc[2][2] = {};

  for (int kc = 0; kc < 8; ++kc) {
    __syncthreads();                    // previous chunk's frag reads done
#pragma unroll
    for (int i = 0; i < 4; ++i) {
      *(s16x8*)&Asm[srow * 136 + sc + i * 8] = ar[i];
      *(s16x8*)&Bsm[srow * 136 + sc + i * 8] = br[i];
    }
    if (kc < 7) {                       // prefetch next chunk over this MFMA
#pragma unroll
      for (int i = 0; i < 4; ++i) {
        ar[i] = *(const s16x8*)(Ag + (kc + 1) * 128 + i * 8);
        br[i] = *(const s16x8*)(Bg + (kc + 1) * 128 + i * 8);
      }
    }
    __syncthreads();
#pragma unroll
    for (int ks = 0; ks < 4; ++ks) {
      s16x8 a0 = *(const s16x8*)&Asm[(wm + lm)      * 136 + ks * 32 + quad * 8];
      s16x8 a1 = *(const s16x8*)&Asm[(wm + 16 + lm) * 136 + ks * 32 + quad * 8];
      s16x8 b0 = *(const s16x8*)&Bsm[(wn + lm)      * 136 + ks * 32 + quad * 8];
      s16x8 b1 = *(const s16x8*)&Bsm[(wn + 16 + lm) * 136 + ks * 32 + quad * 8];
      acc[0][0] = MFMA16(a0, b0, acc[0][0]);
      acc[0][1] = MFMA16(a0, b1, acc[0][1]);
      acc[1][0] = MFMA16(a1, b0, acc[1][0]);
      acc[1][1] = MFMA16(a1, b1, acc[1][1]);
    }
  }

  // epilogue: C/D layout col=lane&15, row=quad*4+reg -> bf16 p
  short* P = (short*)(ws + OFF_PBF);
#pragma unroll
  for (int mi = 0; mi < 2; ++mi)
#pragma unroll
    for (int ni = 0; ni < 2; ++ni) {
      int col = n0 + wn + ni * 16 + lm;
      float bcv = bc[col];
#pragma unroll
      for (int r = 0; r < 4; ++r) {
        int row = m0 + wm + mi * 16 + quad * 4 + r;
        P[(unsigned)row * 256u + col] = f2bf(fmaxf(acc[mi][ni][r] + bcv, 0.f));
      }
    }
}

// ============================================================================
// K2: two heads via bf16 MFMA, 144 blocks x 32 rows, both stages fused.
// Protein A-tiles copied directly from bf16 p (no conversion). Head-2 outputs
// transposed via LDS (ftrans) -> contiguous float4 stores to paT/raT.
// ============================================================================
__global__ __launch_bounds__(TPB, 2) void k2_heads(
    const float* __restrict__ reactions,
    const float* __restrict__ W1,  const float* __restrict__ b1,
    const float* __restrict__ W2,  const float* __restrict__ b2,
    const float* __restrict__ Wpa, const float* __restrict__ bpa,
    const float* __restrict__ Wra, const float* __restrict__ bra,
    float* __restrict__ ws)
{
  __shared__ __align__(16) short Asm[32 * 264];   // src rows [32][256+8]
  __shared__ __align__(16) short Bsm[64 * 264];   // W1/W2 [64][256+8]
  __shared__ __align__(16) short Ksm[32 * 72];    // k-tile bf16 [32][64+8]
  __shared__ __align__(16) short Wsm[64 * 72];    // Wpa/Wra [64][64+8]
  __shared__ float ftrans[64 * 33];               // head2 transpose [col][row]
  int bid = blockIdx.x, tid = threadIdx.x;
  bool isProt = bid < 128;
  int row0 = (isProt ? bid : (bid - 128)) * 32;
  const float* Wst1 = isProt ? W1 : W2;
  const float* bv   = isProt ? b1 : b2;
  const float* Wst2 = isProt ? Wpa : Wra;
  const float* b2nd = isProt ? bpa : bra;
  float* out1  = ws + (isProt ? OFF_K : OFF_R);
  float* out2T = ws + (isProt ? OFF_PAT : OFF_RAT);
  unsigned tstride = isProt ? 4096u : 512u;

  if (isProt) {                         // stage A from bf16 p: pure copy
    int row = tid >> 3, seg = (tid & 7) * 32;
    const short* sp = (const short*)(ws + OFF_PBF) +
                      (size_t)(row0 + row) * 256 + seg;
#pragma unroll
    for (int i = 0; i < 4; ++i)
      *(s16x8*)&Asm[row * 264 + seg + i * 8] = *(const s16x8*)(sp + i * 8);
  } else {                              // stage A from reactions fp32 -> bf16
    int row = tid >> 3, seg = (tid & 7) * 32;
    const float* sp = reactions + (size_t)(row0 + row) * 256 + seg;
    float4 f[8];
#pragma unroll
    for (int i = 0; i < 8; ++i) f[i] = *(const float4*)(sp + i * 4);
#pragma unroll
    for (int i = 0; i < 4; ++i) {
      U8 s;
      s.u[0] = pkbf(f[2*i].x,   f[2*i].y);
      s.u[1] = pkbf(f[2*i].z,   f[2*i].w);
      s.u[2] = pkbf(f[2*i+1].x, f[2*i+1].y);
      s.u[3] = pkbf(f[2*i+1].z, f[2*i+1].w);
      *(s16x8*)&Asm[row * 264 + seg + i * 8] = s.s;
    }
  }
  {                                     // stage B = W1/W2 [64][256]
    int row = tid >> 2, seg = (tid & 3) * 64;
    const float* sp = Wst1 + (size_t)row * 256 + seg;
#pragma unroll
    for (int i = 0; i < 8; ++i) {
      float4 fa = *(const float4*)(sp + i * 8);
      float4 fb = *(const float4*)(sp + i * 8 + 4);
      U8 s;
      s.u[0] = pkbf(fa.x, fa.y); s.u[1] = pkbf(fa.z, fa.w);
      s.u[2] = pkbf(fb.x, fb.y); s.u[3] = pkbf(fb.z, fb.w);
      *(s16x8*)&Bsm[row * 264 + seg + i * 8] = s.s;
    }
  }
  {                                     // stage Wpa/Wra [64][64]
    int row = tid >> 2, seg = (tid & 3) * 16;
    const float* sp = Wst2 + (size_t)row * 64 + seg;
#pragma unroll
    for (int i = 0; i < 2; ++i) {
      float4 fa = *(const float4*)(sp + i * 8);
      float4 fb = *(const float4*)(sp + i * 8 + 4);
      U8 s;
      s.u[0] = pkbf(fa.x, fa.y); s.u[1] = pkbf(fa.z, fa.w);
      s.u[2] = pkbf(fb.x, fb.y); s.u[3] = pkbf(fb.z, fb.w);
      *(s16x8*)&Wsm[row * 72 + seg + i * 8] = s.s;
    }
  }
  __syncthreads();

  int wave = tid >> 6, lane = tid & 63;
  int lm = lane & 15, quad = lane >> 4;
  int wm = (wave >> 1) * 16, wn = (wave & 1) * 32;   // wave tile 16x32

  f32x4 acc[2] = {};
#pragma unroll
  for (int kc = 0; kc < 8; ++kc) {
    s16x8 a = *(const s16x8*)&Asm[(wm + lm) * 264 + kc * 32 + quad * 8];
#pragma unroll
    for (int ni = 0; ni < 2; ++ni) {
      s16x8 b = *(const s16x8*)&Bsm[(wn + ni * 16 + lm) * 264 + kc * 32 + quad * 8];
      acc[ni] = MFMA16(a, b, acc[ni]);
    }
  }
  // epilogue 1: k = relu(acc + b); fp32 -> ws, bf16 -> Ksm (A-layout)
#pragma unroll
  for (int ni = 0; ni < 2; ++ni) {
    int col = wn + ni * 16 + lm;
    float bb = bv[col];
#pragma unroll
    for (int r = 0; r < 4; ++r) {
      int row = wm + quad * 4 + r;
      float kv = fmaxf(acc[ni][r] + bb, 0.f);
      out1[(size_t)(row0 + row) * 64 + col] = kv;
      Ksm[row * 72 + col] = f2bf(kv);
    }
  }
  __syncthreads();

  f32x4 acc2[2] = {};
#pragma unroll
  for (int kc = 0; kc < 2; ++kc) {
    s16x8 a = *(const s16x8*)&Ksm[(wm + lm) * 72 + kc * 32 + quad * 8];
#pragma unroll
    for (int ni = 0; ni < 2; ++ni) {
      s16x8 b = *(const s16x8*)&Wsm[(wn + ni * 16 + lm) * 72 + kc * 32 + quad * 8];
      acc2[ni] = MFMA16(a, b, acc2[ni]);
    }
  }
  // head2 -> LDS transpose [col][row]
#pragma unroll
  for (int ni = 0; ni < 2; ++ni) {
    int col = wn + ni * 16 + lm;
    float bb = b2nd[col];
#pragma unroll
    for (int r = 0; r < 4; ++r) {
      int row = wm + quad * 4 + r;
      ftrans[col * 33 + row] = acc2[ni][r] + bb;
    }
  }
  __syncthreads();
  {                                     // coalesced stores: 2x float4 per thread
    int colc = tid >> 2, seg = (tid & 3) * 8;
    float t0 = ftrans[colc * 33 + seg + 0], t1 = ftrans[colc * 33 + seg + 1];
    float t2 = ftrans[colc * 33 + seg + 2], t3 = ftrans[colc * 33 + seg + 3];
    float t4 = ftrans[colc * 33 + seg + 4], t5 = ftrans[colc * 33 + seg + 5];
    float t6 = ftrans[colc * 33 + seg + 6], t7 = ftrans[colc * 33 + seg + 7];
    float* dp = out2T + (size_t)colc * tstride + row0 + seg;
    *(float4*)dp       = make_float4(t0, t1, t2, t3);
    *(float4*)(dp + 4) = make_float4(t4, t5, t6, t7);
  }
}

// ============================================================================
// K3h: histogram interaction sums. 128 blocks; columns staged from the k2-
// written transposed copies as contiguous coalesced float4 reads.
//   Sr[q,c] = u*cnt(x > -u) + sum(x > -u) via 1024-bin hist + suffix scan.
//   bid<64 : pass A -> SRT[c][512] (coalesced stores)
//   bid>=64: pass B -> SPT[c][4096] (coalesced stores)
// ============================================================================
__global__ __launch_bounds__(TPB) void k3h_hist(float* __restrict__ ws)
{
  __shared__ float xcol[4096];          // pa column
  __shared__ float rcol[512];           // ra column
  __shared__ float hc[1025];            // bin counts -> suffix counts
  __shared__ float hs[1025];            // bin sums   -> suffix sums
  __shared__ float rmn[4], rmx[4];
  int bid = blockIdx.x, tid = threadIdx.x;
  int wave = tid >> 6, lane = tid & 63;
  bool passA = bid < 64;
  int c = passA ? bid : (bid - 64);
  const float* paT = ws + OFF_PAT + (size_t)c * 4096;
  const float* raT = ws + OFF_RAT + (size_t)c * 512;

  for (int i = tid * 4; i < 4096; i += TPB * 4)
    *(float4*)&xcol[i] = *(const float4*)(paT + i);
  if (tid * 4 < 512)
    *(float4*)&rcol[tid * 4] = *(const float4*)(raT + tid * 4);
  for (int i = tid; i < 1025; i += TPB) { hc[i] = 0.f; hs[i] = 0.f; }
  __syncthreads();

  const float* hsrc = passA ? xcol : rcol;  // histogram source
  int hn = passA ? 4096 : 512;
  float mn = 1e30f, mx = -1e30f;
  for (int i = tid; i < hn; i += TPB) {
    float x = hsrc[i];
    mn = fminf(mn, x); mx = fmaxf(mx, x);
  }
#pragma unroll
  for (int off = 32; off > 0; off >>= 1) {
    mn = fminf(mn, __shfl_down(mn, off));
    mx = fmaxf(mx, __shfl_down(mx, off));
  }
  if (lane == 0) { rmn[wave] = mn; rmx[wave] = mx; }
  __syncthreads();
  mn = fminf(fminf(rmn[0], rmn[1]), fminf(rmn[2], rmn[3]));
  mx = fmaxf(fmaxf(rmx[0], rmx[1]), fmaxf(rmx[2], rmx[3]));
  float w = (mx - mn) * (1.f / 1024.f);
  float invw = (w > 1e-30f) ? 1.f / w : 0.f;
  for (int i = tid; i < hn; i += TPB) {
    float x = hsrc[i];
    int b = (int)((x - mn) * invw);
    b = b < 0 ? 0 : (b > 1023 ? 1023 : b);
    atomicAdd(&hc[b], 1.f);
    atomicAdd(&hs[b], x);
  }
  __syncthreads();
  if (wave == 0) {                      // suffix scan, 16 bins/lane + shfl
    float vc[16], vs[16], sc = 0.f, ss = 0.f;
#pragma unroll
    for (int i = 0; i < 16; ++i) {
      vc[i] = hc[lane * 16 + i]; sc += vc[i];
      vs[i] = hs[lane * 16 + i]; ss += vs[i];
    }
    float tc = sc, ts = ss;
#pragma unroll
    for (int off = 1; off < 64; off <<= 1) {
      float oc = __shfl_down(tc, off);
      float os = __shfl_down(ts, off);
      if (lane + off < 64) { tc += oc; ts += os; }
    }
    float runc = tc - sc, runs = ts - ss;
#pragma unroll
    for (int i = 15; i >= 0; --i) {
      runc += vc[i]; hc[lane * 16 + i] = runc;
      runs += vs[i]; hs[lane * 16 + i] = runs;
    }
  }
  __syncthreads();                      // hc/hs = inclusive suffix; [1024]=0

  if (passA) {                          // 512 SR queries -> SRT[c][q] coalesced
    for (int q = tid; q < 512; q += TPB) {
      float u = rcol[q];
      float thr = -u;
      int b;
      if (thr < mn) b = 0;
      else { b = (int)((thr - mn) * invw) + 1; b = b > 1024 ? 1024 : b; }
      ws[OFF_SRT + (unsigned)c * 512u + q] = u * hc[b] + hs[b];
    }
  } else {                              // 4096 SP queries -> SPT[c][l] coalesced
    for (int l = tid; l < 4096; l += TPB) {
      float v = xcol[l];
      float thr = -v;
      int b;
      if (thr < mn) b = 0;
      else { b = (int)((thr - mn) * invw) + 1; b = b > 1024 ? 1024 : b; }
      ws[OFF_SPT + (unsigned)c * 4096u + l] = v * hc[b] + hs[b];
    }
  }
}

// ============================================================================
// K3b: gate pass. 256 blocks x 16 l-rows:
// p_gate = sigmoid(SP/512 @ Wa^T + ba); val = k*(1+gate); atomicMax PMAX.
// SP staged from transposed SPT (small strided tile, L2-resident).
// ============================================================================
__global__ __launch_bounds__(TPB) void k3b_gate(
    const float* __restrict__ Wa, const float* __restrict__ ba,
    float* __restrict__ ws)
{
  __shared__ float sp[16 * 64];
  __shared__ float wat[64 * 65];
  int bid = blockIdx.x, tid = threadIdx.x;
  int c = tid & 63, g = tid >> 6;
  int l0 = bid * 16;
  {                                     // stage SP tile from SPT (x 1/512)
    int cc = tid >> 2, part = tid & 3;
    float4 v = *(const float4*)&ws[OFF_SPT + (unsigned)cc * 4096u + l0 + part * 4];
    sp[(part * 4 + 0) * 64 + cc] = v.x * (1.f / 512.f);
    sp[(part * 4 + 1) * 64 + cc] = v.y * (1.f / 512.f);
    sp[(part * 4 + 2) * 64 + cc] = v.z * (1.f / 512.f);
    sp[(part * 4 + 3) * 64 + cc] = v.w * (1.f / 512.f);
  }
  for (int it = 0; it < 16; ++it) {     // WaT[c'][j] = Wa[j][c']
    int idx = it * TPB + tid;
    wat[(idx & 63) * 65 + (idx >> 6)] = Wa[idx];
  }
  __syncthreads();
  float vmax = 0.f;                     // vals >= 0 (k>=0, gate>0)
  float bac = ba[c];
#pragma unroll
  for (int i = 0; i < 4; ++i) {
    int ll = g * 4 + i;
    float dot = 0.f;
#pragma unroll 8
    for (int jj = 0; jj < 64; ++jj)
      dot += sp[ll * 64 + jj] * wat[jj * 65 + c];
    float pg = 1.f / (1.f + __expf(-(dot + bac)));
    float val = ws[OFF_K + (unsigned)(l0 + ll) * 64u + c] * (1.f + pg);
    vmax = fmaxf(vmax, val);
  }
  atomicMax((int*)&ws[OFF_PMAX + c], __float_as_int(vmax));
}

// ============================================================================
// K4: merged final stage, 32 blocks x 16 q. All matmul-shaped pieces as MFMA.
// mr staged from transposed SRT.
// ============================================================================
__global__ __launch_bounds__(TPB) void k4_final(
    const float* __restrict__ Wa,  const float* __restrict__ ba,
    const float* __restrict__ Wf1, const float* __restrict__ bf1,
    const float* __restrict__ Wf2, const float* __restrict__ bf2,
    const float* __restrict__ Wf3, const float* __restrict__ bf3,
    float* __restrict__ ws, float* __restrict__ out)
{
  __shared__ __align__(16) short mrb[16 * 72];     // mr bf16 (A for gate)
  __shared__ __align__(16) short wab[64 * 72];     // Wa bf16 (B for gate)
  __shared__ __align__(16) short ctxb[16 * 136];   // ctx bf16 (A for h1)
  __shared__ __align__(16) short h1b[16 * 264];    // h1 bf16 (A for h2)
  __shared__ __align__(16) short wgt[256 * 136];   // Wf1 [256][136] then Wf2 [128][264]
  __shared__ float red[64];
  int bid = blockIdx.x, tid = threadIdx.x;
  int q0 = bid * 16;
  int wave = tid >> 6, lane = tid & 63;
  int lm = lane & 15, quad = lane >> 4;

  {                                     // stage mr = SRT/4096 -> bf16 [16][72]
    int cc = tid >> 2, part = tid & 3;
    float4 v = *(const float4*)&ws[OFF_SRT + (unsigned)cc * 512u + q0 + part * 4];
    mrb[(part * 4 + 0) * 72 + cc] = f2bf(v.x * (1.f / 4096.f));
    mrb[(part * 4 + 1) * 72 + cc] = f2bf(v.y * (1.f / 4096.f));
    mrb[(part * 4 + 2) * 72 + cc] = f2bf(v.z * (1.f / 4096.f));
    mrb[(part * 4 + 3) * 72 + cc] = f2bf(v.w * (1.f / 4096.f));
  }
#pragma unroll
  for (int it = 0; it < 4; ++it) {      // stage Wa [64][64] -> bf16 [64][72]
    int i4 = it * TPB + tid;
    int row = i4 >> 4, c4 = (i4 & 15) * 4;
    float4 v = *(const float4*)&Wa[row * 64 + c4];
    uint2 st = make_uint2(pkbf(v.x, v.y), pkbf(v.z, v.w));
    *(uint2*)&wab[row * 72 + c4] = st;
  }
  __syncthreads();

  // gate MFMA: wave w -> c-tile [w*16, w*16+16)
  f32x4 gacc = {};
#pragma unroll
  for (int kc = 0; kc < 2; ++kc) {
    s16x8 a = *(const s16x8*)&mrb[lm * 72 + kc * 32 + quad * 8];
    s16x8 b = *(const s16x8*)&wab[(wave * 16 + lm) * 72 + kc * 32 + quad * 8];
    gacc = MFMA16(a, b, gacc);
  }
  {                                     // epilogue: rx + prot halves -> ctxb
    int c = wave * 16 + lm;
    float bac = ba[c];
    short pb = f2bf(ws[OFF_PMAX + c]);  // prot[c] (atomicMax result)
#pragma unroll
    for (int r = 0; r < 4; ++r) {
      int q = quad * 4 + r;
      float gg = 1.f / (1.f + __expf(-(gacc[r] + bac)));
      float rv = ws[OFF_R + (unsigned)(q0 + q) * 64u + c];
      ctxb[q * 136 + c]      = f2bf(rv * (1.f + gg));
      ctxb[q * 136 + 64 + c] = pb;
    }
  }
#pragma unroll 4
  for (int it = 0; it < 32; ++it) {     // stage Wf1 [256][128] -> wgt [256][136]
    int i4 = it * TPB + tid;
    int row = i4 >> 5, c4 = (i4 & 31) * 4;
    float4 v = *(const float4*)&Wf1[row * 128 + c4];
    uint2 st = make_uint2(pkbf(v.x, v.y), pkbf(v.z, v.w));
    *(uint2*)&wgt[row * 136 + c4] = st;
  }
  __syncthreads();

  // h1 MFMA: wave w covers n in [w*64, w*64+64): 4 n-tiles x 4 k-chunks
  f32x4 h[4] = {};
#pragma unroll
  for (int kc = 0; kc < 4; ++kc) {
    s16x8 a = *(const s16x8*)&ctxb[lm * 136 + kc * 32 + quad * 8];
#pragma unroll
    for (int nt = 0; nt < 4; ++nt) {
      s16x8 b = *(const s16x8*)&wgt[(wave * 64 + nt * 16 + lm) * 136 + kc * 32 + quad * 8];
      h[nt] = MFMA16(a, b, h[nt]);
    }
  }
#pragma unroll
  for (int nt = 0; nt < 4; ++nt) {
    int n = wave * 64 + nt * 16 + lm;
    float bb = bf1[n];
#pragma unroll
    for (int r = 0; r < 4; ++r) {
      int q = quad * 4 + r;
      float v = h[nt][r] + bb;
      v = v > 0.f ? v : 0.01f * v;
      h1b[q * 264 + n] = f2bf(v);
    }
  }
  __syncthreads();                      // h1b complete; wgt reads done

#pragma unroll 4
  for (int it = 0; it < 32; ++it) {     // stage Wf2 [128][256] -> wgt [128][264]
    int i4 = it * TPB + tid;
    int row = i4 >> 6, c4 = (i4 & 63) * 4;
    float4 v = *(const float4*)&Wf2[row * 256 + c4];
    uint2 st = make_uint2(pkbf(v.x, v.y), pkbf(v.z, v.w));
    *(uint2*)&wgt[row * 264 + c4] = st;
  }
  __syncthreads();

  // h2 MFMA: wave w covers m in [w*32, w*32+32): 2 n-tiles x 8 k-chunks
  f32x4 o[2] = {};
#pragma unroll
  for (int kc = 0; kc < 8; ++kc) {
    s16x8 a = *(const s16x8*)&h1b[lm * 264 + kc * 32 + quad * 8];
#pragma unroll
    for (int nt = 0; nt < 2; ++nt) {
      s16x8 b = *(const s16x8*)&wgt[(wave * 32 + nt * 16 + lm) * 264 + kc * 32 + quad * 8];
      o[nt] = MFMA16(a, b, o[nt]);
    }
  }
  float pv[4] = {0.f, 0.f, 0.f, 0.f};
#pragma unroll
  for (int nt = 0; nt < 2; ++nt) {
    int m = wave * 32 + nt * 16 + lm;
    float bb = bf2[m], w3 = Wf3[m];
#pragma unroll
    for (int r = 0; r < 4; ++r) {
      float v = o[nt][r] + bb;
      v = v > 0.f ? v : 0.01f * v;
      pv[r] += v * w3;
    }
  }
#pragma unroll
  for (int msk = 1; msk < 16; msk <<= 1)
#pragma unroll
    for (int r = 0; r < 4; ++r) pv[r] += __shfl_xor(pv[r], msk);
  if (lm == 0) {
#pragma unroll
    for (int r = 0; r < 4; ++r) red[(quad * 4 + r) * 4 + wave] = pv[r];
  }
  __syncthreads();
  if (tid < 16)
    out[q0 + tid] = red[tid * 4] + red[tid * 4 + 1] + red[tid * 4 + 2] +
                    red[tid * 4 + 3] + bf3[0];
}

// ============================================================================
extern "C" void kernel_launch(void* const* d_in, const int* in_sizes, int n_in,
                              void* d_out, int out_size, void* d_ws, size_t ws_size,
                              hipStream_t stream)
{
  const float* reactions = (const float*)d_in[0];
  const float* protein   = (const float*)d_in[1];
  const float* Wc  = (const float*)d_in[2];
  const float* bc  = (const float*)d_in[3];
  const float* W1  = (const float*)d_in[4];
  const float* b1  = (const float*)d_in[5];
  const float* W2  = (const float*)d_in[6];
  const float* b2  = (const float*)d_in[7];
  const float* Wa  = (const float*)d_in[8];
  const float* ba  = (const float*)d_in[9];
  const float* Wpa = (const float*)d_in[10];
  const float* bpa = (const float*)d_in[11];
  const float* Wra = (const float*)d_in[12];
  const float* bra = (const float*)d_in[13];
  const float* Wf1 = (const float*)d_in[14];
  const float* bf1 = (const float*)d_in[15];
  const float* Wf2 = (const float*)d_in[16];
  const float* bf2 = (const float*)d_in[17];
  const float* Wf3 = (const float*)d_in[18];
  const float* bf3 = (const float*)d_in[19];
  float* ws  = (float*)d_ws;
  float* out = (float*)d_out;

  hipLaunchKernelGGL(k0_cvt, dim3(2177), dim3(TPB), 0, stream,
                     protein, Wc, ws);
  hipLaunchKernelGGL(k1_gemm, dim3(256), dim3(TPB), 0, stream,
                     bc, ws);
  hipLaunchKernelGGL(k2_heads, dim3(144), dim3(TPB), 0, stream,
                     reactions, W1, b1, W2, b2, Wpa, bpa, Wra, bra, ws);
  hipLaunchKernelGGL(k3h_hist, dim3(128), dim3(TPB), 0, stream, ws);
  hipLaunchKernelGGL(k3b_gate, dim3(256), dim3(TPB), 0, stream, Wa, ba, ws);
  hipLaunchKernelGGL(k4_final, dim3(32), dim3(TPB), 0, stream,
                     Wa, ba, Wf1, bf1, Wf2, bf2, Wf3, bf3, ws, out);
}